// Round 2
// baseline (311.349 us; speedup 1.0000x reference)
//
#include <hip/hip_runtime.h>
#include <hip/hip_bf16.h>

typedef __bf16 bf16_t;
typedef __attribute__((ext_vector_type(8))) __bf16 bf16x8;
typedef __attribute__((ext_vector_type(4))) float f32x4;

#define BH 64
#define KP 512
#define NN 4096
#define DD 64
#define GSZ (BH * KP * DD)  // offset of gV in d_out

#define MFMA16(a, b, c) __builtin_amdgcn_mfma_f32_16x16x32_bf16((a), (b), (c), 0, 0, 0)

__device__ __forceinline__ bf16x8 cvt8v(const f32x4 lo, const f32x4 hi) {
  bf16x8 r;
  r[0] = (bf16_t)lo[0]; r[1] = (bf16_t)lo[1]; r[2] = (bf16_t)lo[2]; r[3] = (bf16_t)lo[3];
  r[4] = (bf16_t)hi[0]; r[5] = (bf16_t)hi[1]; r[6] = (bf16_t)hi[2]; r[7] = (bf16_t)hi[3];
  return r;
}
__device__ __forceinline__ bf16x8 cvt8(const float* __restrict__ p) {
  return cvt8v(*(const f32x4*)p, *(const f32x4*)(p + 4));
}

// global->LDS DMA, 16B per lane; lds dest is wave-uniform base + lane*16.
__device__ __forceinline__ void stage16(bf16_t* lds_base, const bf16_t* gsrc) {
  __builtin_amdgcn_global_load_lds(
      (const __attribute__((address_space(1))) void*)gsrc,
      (__attribute__((address_space(3))) void*)lds_base, 16, 0, 0);
}

// ---------------------------------------------------------------------------
// Fused pass 1: per block = one (bh, 512-n slice).
//   phase 0: convert/transpose slice -> xk16 (natural), xkT16, xvT16 (prep work)
//   phase 1: stage FULL K slab (512x64) into LDS bf16 once (73.7 KB, 2 blk/CU)
//   phase 2: colsum main loop, BARRIER-FREE (K read-only resident)
// Grid 512 (8 n-blocks x 64 bh), XCD-bijective: same-bh blocks share an XCD L2.
// ---------------------------------------------------------------------------
__global__ __launch_bounds__(256) void hop_pass1f(
    const float* __restrict__ Km, const float* __restrict__ xk,
    const float* __restrict__ xv,
    bf16_t* __restrict__ xk16, bf16_t* __restrict__ xkT16,
    bf16_t* __restrict__ xvT16, float* __restrict__ inv_colsum)
{
  __shared__ __align__(16) bf16_t Ks[512 * 72];  // 73728 B; front reused as T

  const int tid  = threadIdx.x;
  const int wave = tid >> 6, lane = tid & 63;
  const int col  = lane & 15, quad = lane >> 4;
  const int bid  = blockIdx.x;
  const int bh   = (bid & 7) + 8 * ((bid >> 3) & 7);
  const int nblk = (bid >> 6) * 512;

  const float* Kb  = Km + (size_t)bh * KP * DD;
  const float* xkb = xk + (size_t)bh * NN * DD + (size_t)nblk * DD;
  const float* xvb = xv + (size_t)bh * NN * DD + (size_t)nblk * DD;
  bf16_t* xk16b = xk16  + (size_t)bh * NN * DD + (size_t)nblk * DD;
  bf16_t* xkTb  = xkT16 + (size_t)bh * DD * NN + nblk;
  bf16_t* xvTb  = xvT16 + (size_t)bh * DD * NN + nblk;

  bf16_t* T = Ks;  // 64*72 transpose staging (aliases K buffer; phases barriered)

  const int row  = tid >> 2;         // load-phase n within batch
  const int d0   = (tid & 3) * 16;
  const int dcol = tid >> 2;         // transpose-read-phase d
  const int nb   = (tid & 3) * 16;

  // ---- phase 0: prep work for this block's 512-n slice (8 batches of 64) ----
  for (int b = 0; b < 8; b++) {
    {
      const float* src = xkb + (size_t)(b * 64 + row) * DD + d0;
      const f32x4 a0 = *(const f32x4*)(src);
      const f32x4 a1 = *(const f32x4*)(src + 4);
      const f32x4 a2 = *(const f32x4*)(src + 8);
      const f32x4 a3 = *(const f32x4*)(src + 12);
      const bf16x8 lo = cvt8v(a0, a1), hi = cvt8v(a2, a3);
      bf16_t* dn = xk16b + (size_t)(b * 64 + row) * DD + d0;
      *(bf16x8*)(dn)     = lo;
      *(bf16x8*)(dn + 8) = hi;
      *(bf16x8*)(T + row * 72 + d0)     = lo;
      *(bf16x8*)(T + row * 72 + d0 + 8) = hi;
    }
    __syncthreads();
    {
      bf16x8 o0, o1;
      #pragma unroll
      for (int j = 0; j < 8; j++) o0[j] = T[(nb + j) * 72 + dcol];
      #pragma unroll
      for (int j = 0; j < 8; j++) o1[j] = T[(nb + 8 + j) * 72 + dcol];
      bf16_t* dT = xkTb + (size_t)dcol * NN + b * 64 + nb;
      *(bf16x8*)(dT)     = o0;
      *(bf16x8*)(dT + 8) = o1;
    }
    __syncthreads();
    {
      const float* src = xvb + (size_t)(b * 64 + row) * DD + d0;
      const f32x4 a0 = *(const f32x4*)(src);
      const f32x4 a1 = *(const f32x4*)(src + 4);
      const f32x4 a2 = *(const f32x4*)(src + 8);
      const f32x4 a3 = *(const f32x4*)(src + 12);
      *(bf16x8*)(T + row * 72 + d0)     = cvt8v(a0, a1);
      *(bf16x8*)(T + row * 72 + d0 + 8) = cvt8v(a2, a3);
    }
    __syncthreads();
    {
      bf16x8 o0, o1;
      #pragma unroll
      for (int j = 0; j < 8; j++) o0[j] = T[(nb + j) * 72 + dcol];
      #pragma unroll
      for (int j = 0; j < 8; j++) o1[j] = T[(nb + 8 + j) * 72 + dcol];
      bf16_t* dT = xvTb + (size_t)dcol * NN + b * 64 + nb;
      *(bf16x8*)(dT)     = o0;
      *(bf16x8*)(dT + 8) = o1;
    }
    __syncthreads();
  }

  // ---- phase 1: full K slab -> LDS bf16 (pitch 72), single barrier ----
  {
    const int srow = tid >> 1, sdo = (tid & 1) * 32;
    #pragma unroll
    for (int kc = 0; kc < KP; kc += 128) {
      const float* src = Kb + (size_t)(kc + srow) * DD + sdo;
      #pragma unroll
      for (int u = 0; u < 4; u++) {
        const f32x4 p0 = *(const f32x4*)(src + 8 * u);
        const f32x4 p1 = *(const f32x4*)(src + 8 * u + 4);
        *(bf16x8*)(Ks + (size_t)(kc + srow) * 72 + sdo + 8 * u) = cvt8v(p0, p1);
      }
    }
  }
  __syncthreads();

  // ---- phase 2: colsum, barrier-free; wave owns 2 n-tiles of 64 ----
  #pragma unroll
  for (int t = 0; t < 2; t++) {
    const int n0 = wave * 128 + t * 64;  // within slice
    bf16x8 bfr[4][2];
    #pragma unroll
    for (int nsub = 0; nsub < 4; nsub++) {
      const bf16_t* p = xk16b + (size_t)(n0 + nsub * 16 + col) * DD + quad * 8;
      bfr[nsub][0] = *(const bf16x8*)(p);
      bfr[nsub][1] = *(const bf16x8*)(p + 32);
    }
    float colacc[4] = {0.f, 0.f, 0.f, 0.f};
    #pragma unroll 4
    for (int ks = 0; ks < 32; ks++) {
      const bf16x8 a0 = *(const bf16x8*)(Ks + (ks * 16 + col) * 72 + quad * 8);
      const bf16x8 a1 = *(const bf16x8*)(Ks + (ks * 16 + col) * 72 + 32 + quad * 8);
      #pragma unroll
      for (int nsub = 0; nsub < 4; nsub++) {
        f32x4 c = {0.f, 0.f, 0.f, 0.f};
        c = MFMA16(a0, bfr[nsub][0], c);
        c = MFMA16(a1, bfr[nsub][1], c);
        colacc[nsub] += __expf(c[0]) + __expf(c[1]) + __expf(c[2]) + __expf(c[3]);
      }
    }
    #pragma unroll
    for (int nsub = 0; nsub < 4; nsub++) {
      colacc[nsub] += __shfl_xor(colacc[nsub], 16, 64);
      colacc[nsub] += __shfl_xor(colacc[nsub], 32, 64);
    }
    float v = colacc[0];
    v = (quad == 1) ? colacc[1] : v;
    v = (quad == 2) ? colacc[2] : v;
    v = (quad == 3) ? colacc[3] : v;
    inv_colsum[bh * NN + nblk + n0 + quad * 16 + col] = 1.0f / v;
  }
}

// ---------------------------------------------------------------------------
// Pass 2 (unchanged control): bf16 tiles staged via global_load_lds with
// source-side XOR swizzle; double-buffered; XCD-bijective block swizzle.
// ---------------------------------------------------------------------------
#define NT 64
#define PW 72

__global__ __launch_bounds__(256) void hop_pass2(
    const float* __restrict__ Km, const float* __restrict__ Vm,
    const bf16_t* __restrict__ xk16, const bf16_t* __restrict__ xkT16,
    const bf16_t* __restrict__ xvT16,
    const float* __restrict__ inv_colsum, float* __restrict__ out)
{
  __shared__ __align__(16) bf16_t xks[2][NT * DD];  // [n][d] (blocks swizzled)
  __shared__ __align__(16) bf16_t xkT[2][DD * NT];  // [d][n]
  __shared__ __align__(16) bf16_t xvT[2][DD * NT];
  __shared__ __align__(16) bf16_t wt[4][16 * PW];   // per-wave w [k][n]

  const int tid  = threadIdx.x;
  const int wave = tid >> 6, lane = tid & 63;
  const int col  = lane & 15, quad = lane >> 4;
  const int bid  = blockIdx.x;
  const int bh   = (bid & 7) + 8 * ((bid >> 3) & 7);  // same-bh ktiles -> same XCD
  const int k0   = (bid >> 6) * 64 + wave * 16;

  const float*  Kb   = Km    + (size_t)bh * KP * DD;
  const float*  Vb   = Vm    + (size_t)bh * KP * DD;
  const bf16_t* xkb  = xk16  + (size_t)bh * NN * DD;
  const bf16_t* xkTb = xkT16 + (size_t)bh * DD * NN;
  const bf16_t* xvTb = xvT16 + (size_t)bh * DD * NN;
  const float*  inv  = inv_colsum + bh * NN;

  const bf16x8 ak0 = cvt8(Kb + (size_t)(k0 + col) * DD + quad * 8);
  const bf16x8 ak1 = cvt8(Kb + (size_t)(k0 + col) * DD + 32 + quad * 8);

  f32x4 accK[4], accV[4];
  #pragma unroll
  for (int i = 0; i < 4; i++) {
    accK[i] = (f32x4){0.f, 0.f, 0.f, 0.f};
    accV[i] = (f32x4){0.f, 0.f, 0.f, 0.f};
  }
  float rows_part = 0.f;

  const int srl = lane >> 3;                 // row & 7 (swizzle key)
  const int r0  = wave * 16 + srl;
  const int r1  = r0 + 8;
  const int sb  = ((lane & 7) ^ srl) * 8;    // swizzled source block offset
  const int lb0 = (wave * 2 + 0) * 512;
  const int lb1 = (wave * 2 + 1) * 512;

  stage16(&xks[0][lb0], xkb + (size_t)r0 * DD + sb);
  stage16(&xks[0][lb1], xkb + (size_t)r1 * DD + sb);
  stage16(&xkT[0][lb0], xkTb + (size_t)r0 * NN + sb);
  stage16(&xkT[0][lb1], xkTb + (size_t)r1 * NN + sb);
  stage16(&xvT[0][lb0], xvTb + (size_t)r0 * NN + sb);
  stage16(&xvT[0][lb1], xvTb + (size_t)r1 * NN + sb);
  __syncthreads();

  int cur = 0;
  for (int n0 = 0; n0 < NN; n0 += NT) {
    if (n0 + NT < NN) {
      const int nx = n0 + NT;
      const int nb2 = cur ^ 1;
      stage16(&xks[nb2][lb0], xkb + (size_t)(nx + r0) * DD + sb);
      stage16(&xks[nb2][lb1], xkb + (size_t)(nx + r1) * DD + sb);
      stage16(&xkT[nb2][lb0], xkTb + (size_t)r0 * NN + nx + sb);
      stage16(&xkT[nb2][lb1], xkTb + (size_t)r1 * NN + nx + sb);
      stage16(&xvT[nb2][lb0], xvTb + (size_t)r0 * NN + nx + sb);
      stage16(&xvT[nb2][lb1], xvTb + (size_t)r1 * NN + nx + sb);
    }

    float ic[4];
    #pragma unroll
    for (int ns = 0; ns < 4; ns++) ic[ns] = inv[n0 + ns * 16 + col];

    const int key = col & 7;

    f32x4 s[4];
    #pragma unroll
    for (int ns = 0; ns < 4; ns++) {
      const bf16_t* bp = &xks[cur][(ns * 16 + col) * DD];
      const bf16x8 b0 = *(const bf16x8*)(bp + 8 * (quad ^ key));
      const bf16x8 b1 = *(const bf16x8*)(bp + 8 * ((quad + 4) ^ key));
      f32x4 c = {0.f, 0.f, 0.f, 0.f};
      c = MFMA16(ak0, b0, c);
      c = MFMA16(ak1, b1, c);
      s[ns] = c;
    }
    bf16_t* wr = wt[wave];
    #pragma unroll
    for (int ns = 0; ns < 4; ns++) {
      #pragma unroll
      for (int r = 0; r < 4; r++)
        wr[(quad * 4 + r) * PW + ns * 16 + col] = (bf16_t)(__expf(s[ns][r]) * ic[ns]);
    }
    const bf16x8 wa0 = *(const bf16x8*)(wr + col * PW + quad * 8);
    const bf16x8 wa1 = *(const bf16x8*)(wr + col * PW + 32 + quad * 8);
    #pragma unroll
    for (int j = 0; j < 8; j++) rows_part += (float)wa0[j] + (float)wa1[j];

    #pragma unroll
    for (int dt = 0; dt < 4; dt++) {
      const int d = dt * 16 + col;
      const bf16_t* kp = &xkT[cur][d * NT];
      const bf16_t* vp = &xvT[cur][d * NT];
      const bf16x8 bk0 = *(const bf16x8*)(kp + 8 * (quad ^ key));
      const bf16x8 bk1 = *(const bf16x8*)(kp + 8 * ((quad + 4) ^ key));
      const bf16x8 bv0 = *(const bf16x8*)(vp + 8 * (quad ^ key));
      const bf16x8 bv1 = *(const bf16x8*)(vp + 8 * ((quad + 4) ^ key));
      accK[dt] = MFMA16(wa0, bk0, accK[dt]);
      accK[dt] = MFMA16(wa1, bk1, accK[dt]);
      accV[dt] = MFMA16(wa0, bv0, accV[dt]);
      accV[dt] = MFMA16(wa1, bv1, accV[dt]);
    }

    __syncthreads();
    cur ^= 1;
  }

  float rs = rows_part;
  rs += __shfl_xor(rs, 16, 64);
  rs += __shfl_xor(rs, 32, 64);
  float invrs[4];
  #pragma unroll
  for (int r = 0; r < 4; r++) invrs[r] = 1.0f / __shfl(rs, quad * 4 + r, 64);

  const size_t base = (size_t)bh * KP * DD;
  #pragma unroll
  for (int dt = 0; dt < 4; dt++) {
    #pragma unroll
    for (int r = 0; r < 4; r++) {
      const int k = k0 + quad * 4 + r;
      const int d = dt * 16 + col;
      const size_t idx = base + (size_t)k * DD + d;
      out[idx]       = accK[dt][r] * invrs[r] - Kb[(size_t)k * DD + d];
      out[GSZ + idx] = accV[dt][r] * invrs[r] - Vb[(size_t)k * DD + d];
    }
  }
}

// ---------------------------------------------------------------------------
// Fallback path (ws too small for bf16 scratch): previous verified kernels.
// ---------------------------------------------------------------------------
__global__ __launch_bounds__(256) void hop_pass1_fb(
    const float* __restrict__ Km, const float* __restrict__ xk,
    float* __restrict__ inv_colsum)
{
  __shared__ __align__(16) bf16_t Ks[128 * 72];
  const int tid  = threadIdx.x;
  const int wave = tid >> 6, lane = tid & 63;
  const int col  = lane & 15, quad = lane >> 4;
  const int bh = blockIdx.y;
  const int n0 = blockIdx.x * 256 + wave * 64;
  const float* Kb  = Km + (size_t)bh * KP * DD;
  const float* xkb = xk + (size_t)bh * NN * DD;
  bf16x8 bf[4][2];
  #pragma unroll
  for (int nsub = 0; nsub < 4; nsub++) {
    const float* p = xkb + (size_t)(n0 + nsub * 16 + col) * DD + quad * 8;
    bf[nsub][0] = cvt8(p);
    bf[nsub][1] = cvt8(p + 32);
  }
  float colacc[4] = {0.f, 0.f, 0.f, 0.f};
  const int srow = tid >> 1, sdo = (tid & 1) * 32;
  for (int kc = 0; kc < KP; kc += 128) {
    __syncthreads();
    const float* src = Kb + (size_t)(kc + srow) * DD + sdo;
    #pragma unroll
    for (int u = 0; u < 4; u++) {
      const f32x4 p0 = *(const f32x4*)(src + 8 * u);
      const f32x4 p1 = *(const f32x4*)(src + 8 * u + 4);
      *(bf16x8*)(Ks + srow * 72 + sdo + 8 * u) = cvt8v(p0, p1);
    }
    __syncthreads();
    #pragma unroll
    for (int ks = 0; ks < 8; ks++) {
      const bf16x8 a0 = *(const bf16x8*)(Ks + (ks * 16 + col) * 72 + quad * 8);
      const bf16x8 a1 = *(const bf16x8*)(Ks + (ks * 16 + col) * 72 + 32 + quad * 8);
      #pragma unroll
      for (int nsub = 0; nsub < 4; nsub++) {
        f32x4 c = {0.f, 0.f, 0.f, 0.f};
        c = MFMA16(a0, bf[nsub][0], c);
        c = MFMA16(a1, bf[nsub][1], c);
        colacc[nsub] += __expf(c[0]) + __expf(c[1]) + __expf(c[2]) + __expf(c[3]);
      }
    }
  }
  #pragma unroll
  for (int nsub = 0; nsub < 4; nsub++) {
    colacc[nsub] += __shfl_xor(colacc[nsub], 16, 64);
    colacc[nsub] += __shfl_xor(colacc[nsub], 32, 64);
  }
  float v = colacc[0];
  v = (quad == 1) ? colacc[1] : v;
  v = (quad == 2) ? colacc[2] : v;
  v = (quad == 3) ? colacc[3] : v;
  inv_colsum[bh * NN + n0 + quad * 16 + col] = 1.0f / v;
}

__global__ __launch_bounds__(256) void hop_pass2_fb(
    const float* __restrict__ Km, const float* __restrict__ Vm,
    const float* __restrict__ xk, const float* __restrict__ xv,
    const float* __restrict__ inv_colsum, float* __restrict__ out)
{
  __shared__ __align__(16) bf16_t xksf[NT * PW];
  __shared__ __align__(16) bf16_t xkTf[DD * NT];
  __shared__ __align__(16) bf16_t xvTf[DD * NT];
  __shared__ __align__(16) bf16_t wtf[4][16 * PW];

  const int tid  = threadIdx.x;
  const int wave = tid >> 6, lane = tid & 63;
  const int col  = lane & 15, quad = lane >> 4;
  const int bh   = blockIdx.x >> 3;
  const int k0   = (blockIdx.x & 7) * 64 + wave * 16;

  const float* Kb  = Km + (size_t)bh * KP * DD;
  const float* Vb  = Vm + (size_t)bh * KP * DD;
  const float* xkb = xk + (size_t)bh * NN * DD;
  const float* xvb = xv + (size_t)bh * NN * DD;
  const float* inv = inv_colsum + bh * NN;

  const bf16x8 ak0 = cvt8(Kb + (size_t)(k0 + col) * DD + quad * 8);
  const bf16x8 ak1 = cvt8(Kb + (size_t)(k0 + col) * DD + 32 + quad * 8);

  f32x4 accK[4], accV[4];
  #pragma unroll
  for (int i = 0; i < 4; i++) {
    accK[i] = (f32x4){0.f, 0.f, 0.f, 0.f};
    accV[i] = (f32x4){0.f, 0.f, 0.f, 0.f};
  }
  float rows_part = 0.f;

  const int sn = tid >> 2;
  const int sd = (tid & 3) * 16;
  const int shi = sn >> 3, slo = sn & 7;

  for (int n0 = 0; n0 < NN; n0 += NT) {
    f32x4 gk[4], gv[4];
    #pragma unroll
    for (int u = 0; u < 4; u++) {
      gk[u] = *(const f32x4*)(xkb + (size_t)(n0 + sn) * DD + sd + 4 * u);
      gv[u] = *(const f32x4*)(xvb + (size_t)(n0 + sn) * DD + sd + 4 * u);
    }
    float ic[4];
    #pragma unroll
    for (int nsub = 0; nsub < 4; nsub++) ic[nsub] = inv[n0 + nsub * 16 + col];

    __syncthreads();
    *(bf16x8*)(xksf + sn * PW + sd)     = cvt8v(gk[0], gk[1]);
    *(bf16x8*)(xksf + sn * PW + sd + 8) = cvt8v(gk[2], gk[3]);
    #pragma unroll
    for (int j = 0; j < 16; j++) {
      const int d   = sd + j;
      const int off = d * NT + (((shi) ^ (d >> 3)) << 3) + slo;
      xkTf[off] = (bf16_t)gk[j >> 2][j & 3];
      xvTf[off] = (bf16_t)gv[j >> 2][j & 3];
    }
    __syncthreads();

    f32x4 s[4];
    #pragma unroll
    for (int nsub = 0; nsub < 4; nsub++) {
      const bf16x8 b0 = *(const bf16x8*)(xksf + (nsub * 16 + col) * PW + quad * 8);
      const bf16x8 b1 = *(const bf16x8*)(xksf + (nsub * 16 + col) * PW + 32 + quad * 8);
      f32x4 c = {0.f, 0.f, 0.f, 0.f};
      c = MFMA16(ak0, b0, c);
      c = MFMA16(ak1, b1, c);
      s[nsub] = c;
    }
    bf16_t* wr = wtf[wave];
    #pragma unroll
    for (int nsub = 0; nsub < 4; nsub++) {
      #pragma unroll
      for (int r = 0; r < 4; r++)
        wr[(quad * 4 + r) * PW + nsub * 16 + col] = (bf16_t)(__expf(s[nsub][r]) * ic[nsub]);
    }
    const bf16x8 wa0 = *(const bf16x8*)(wr + col * PW + quad * 8);
    const bf16x8 wa1 = *(const bf16x8*)(wr + col * PW + 32 + quad * 8);
    #pragma unroll
    for (int j = 0; j < 8; j++) rows_part += (float)wa0[j] + (float)wa1[j];

    #pragma unroll
    for (int dt = 0; dt < 4; dt++) {
      const int d = dt * 16 + col, dhi = d >> 3;
      const bf16x8 bk0 = *(const bf16x8*)(xkTf + d * NT + ((quad ^ dhi) << 3));
      const bf16x8 bk1 = *(const bf16x8*)(xkTf + d * NT + (((4 + quad) ^ dhi) << 3));
      const bf16x8 bv0 = *(const bf16x8*)(xvTf + d * NT + ((quad ^ dhi) << 3));
      const bf16x8 bv1 = *(const bf16x8*)(xvTf + d * NT + (((4 + quad) ^ dhi) << 3));
      accK[dt] = MFMA16(wa0, bk0, accK[dt]);
      accK[dt] = MFMA16(wa1, bk1, accK[dt]);
      accV[dt] = MFMA16(wa0, bv0, accV[dt]);
      accV[dt] = MFMA16(wa1, bv1, accV[dt]);
    }
  }

  float rs = rows_part;
  rs += __shfl_xor(rs, 16, 64);
  rs += __shfl_xor(rs, 32, 64);
  float invrs[4];
  #pragma unroll
  for (int r = 0; r < 4; r++) invrs[r] = 1.0f / __shfl(rs, quad * 4 + r, 64);

  const size_t base = (size_t)bh * KP * DD;
  #pragma unroll
  for (int dt = 0; dt < 4; dt++) {
    #pragma unroll
    for (int r = 0; r < 4; r++) {
      const int k = k0 + quad * 4 + r;
      const int d = dt * 16 + col;
      const size_t idx = base + (size_t)k * DD + d;
      out[idx]       = accK[dt][r] * invrs[r] - Kb[(size_t)k * DD + d];
      out[GSZ + idx] = accV[dt][r] * invrs[r] - Vb[(size_t)k * DD + d];
    }
  }
}

extern "C" void kernel_launch(void* const* d_in, const int* in_sizes, int n_in,
                              void* d_out, int out_size, void* d_ws, size_t ws_size,
                              hipStream_t stream)
{
  (void)in_sizes; (void)n_in; (void)out_size;
  const float* Km = (const float*)d_in[0];
  const float* Vm = (const float*)d_in[1];
  const float* xk = (const float*)d_in[2];
  const float* xv = (const float*)d_in[3];
  float* out = (float*)d_out;
  float* inv_colsum = (float*)d_ws;  // BH*NN floats = 1 MB

  const size_t SCRE = (size_t)BH * NN * DD;  // elems per bf16 scratch array
  const size_t NEED = (size_t)BH * NN * sizeof(float) + 3 * SCRE * sizeof(bf16_t);

  if (ws_size >= NEED) {
    bf16_t* xk16  = (bf16_t*)((char*)d_ws + (size_t)BH * NN * sizeof(float));
    bf16_t* xkT16 = xk16 + SCRE;
    bf16_t* xvT16 = xkT16 + SCRE;
    hop_pass1f<<<dim3(512), 256, 0, stream>>>(Km, xk, xv, xk16, xkT16, xvT16,
                                              inv_colsum);
    hop_pass2<<<dim3(BH * (KP / 64)), 256, 0, stream>>>(Km, Vm, xk16, xkT16, xvT16,
                                                        inv_colsum, out);
  } else {
    hop_pass1_fb<<<dim3(NN / 256, BH), 256, 0, stream>>>(Km, xk, inv_colsum);
    hop_pass2_fb<<<dim3(BH * (KP / 64)), 256, 0, stream>>>(Km, Vm, xk, xv,
                                                           inv_colsum, out);
  }
}